// Round 9
// baseline (90.310 us; speedup 1.0000x reference)
//
#include <hip/hip_runtime.h>

typedef _Float16 f16x8 __attribute__((ext_vector_type(8)));
typedef float f32x16 __attribute__((ext_vector_type(16)));

static __device__ __forceinline__ unsigned cvtpk_u(float a, float b) {
    unsigned r;
    asm("v_cvt_pkrtz_f16_f32 %0, %1, %2" : "=v"(r) : "v"(a), "v"(b));
    return r;
}
static __device__ __forceinline__ f16x8 mk_frag(unsigned a, unsigned b, unsigned c, unsigned d) {
    union { unsigned u[4]; f16x8 v; } x;
    x.u[0]=a; x.u[1]=b; x.u[2]=c; x.u[3]=d; return x.v;
}

// Scalar f32 rational tanh — 11 full-rate VALU ops, no trans, no division.
// tanh x ~= x*(945 + 105u + u^2)/(945 + 420u + 15u^2), u=x^2 (Pade 5/4,
// max err ~1.3e-3, always >=1 in magnitude for |x|>3.8 => med3 clamp exact
// saturation). Division via int-magic rcp + 1 Newton (rel err <= ~3.4e-3).
// Verified numerics anchor: R7 passed with this polynomial (absmax 2.4e-4).
static __device__ __forceinline__ float tanh_rat(float x) {
    float u = x * x;
    float n = fmaf(fmaf(u, 0.015625f, 1.640625f), u, 14.765625f);
    float d = fmaf(fmaf(u, 0.234375f, 6.5625f),   u, 14.765625f);
    float r0 = __uint_as_float(0x7EF127EAu - __float_as_uint(d));
    float r  = r0 * fmaf(-d, r0, 2.0f);          // 1 Newton step
    return __builtin_amdgcn_fmed3f(x * n * r, -1.0f, 1.0f);
}

static __device__ __forceinline__ float mlp_f(float e, float g,
        f16x8 A1, const f32x16& b1v,
        f16x8 A20, f16x8 A21, const f32x16& b2v,
        const f32x16& w3v, float b3v)
{
    // L1 B-operand: k0=e, k1=g, rest 0
    unsigned w0 = cvtpk_u(e, g);
    auto s0 = __builtin_amdgcn_permlane32_swap((int)w0, 0, false, false);
    f16x8 Bg1 = mk_frag((unsigned)s0[0], 0u, 0u, 0u);
    f16x8 Bg2 = mk_frag((unsigned)s0[1], 0u, 0u, 0u);
    f32x16 d1 = __builtin_amdgcn_mfma_f32_32x32x16_f16(A1, Bg1, b1v, 0, 0, 0);
    f32x16 d2 = __builtin_amdgcn_mfma_f32_32x32x16_f16(A1, Bg2, b1v, 0, 0, 0);

    // h1 = tanh(pre1) in f32, packed to f16 pairs for the L2 B-operand
    unsigned P[8], Q[8];
#pragma unroll
    for (int m = 0; m < 8; ++m) {
        P[m] = cvtpk_u(tanh_rat(d1[2*m]), tanh_rat(d1[2*m+1]));
        Q[m] = cvtpk_u(tanh_rat(d2[2*m]), tanh_rat(d2[2*m+1]));
    }

    // L2: pre2^T = W2^T @ h1^T + b2 (permlane routing verified R5/R7/R8)
    f32x16 a1, a2;
    {
        auto u02 = __builtin_amdgcn_permlane32_swap((int)P[0], (int)P[2], false, false);
        auto u13 = __builtin_amdgcn_permlane32_swap((int)P[1], (int)P[3], false, false);
        f16x8 Bq = mk_frag((unsigned)u02[0], (unsigned)u13[0], (unsigned)u02[1], (unsigned)u13[1]);
        a1 = __builtin_amdgcn_mfma_f32_32x32x16_f16(A20, Bq, b2v, 0, 0, 0);
        auto v02 = __builtin_amdgcn_permlane32_swap((int)P[4], (int)P[6], false, false);
        auto v13 = __builtin_amdgcn_permlane32_swap((int)P[5], (int)P[7], false, false);
        f16x8 Br = mk_frag((unsigned)v02[0], (unsigned)v13[0], (unsigned)v02[1], (unsigned)v13[1]);
        a1 = __builtin_amdgcn_mfma_f32_32x32x16_f16(A21, Br, a1, 0, 0, 0);
    }
    {
        auto u02 = __builtin_amdgcn_permlane32_swap((int)Q[0], (int)Q[2], false, false);
        auto u13 = __builtin_amdgcn_permlane32_swap((int)Q[1], (int)Q[3], false, false);
        f16x8 Bq = mk_frag((unsigned)u02[0], (unsigned)u13[0], (unsigned)u02[1], (unsigned)u13[1]);
        a2 = __builtin_amdgcn_mfma_f32_32x32x16_f16(A20, Bq, b2v, 0, 0, 0);
        auto v02 = __builtin_amdgcn_permlane32_swap((int)Q[4], (int)Q[6], false, false);
        auto v13 = __builtin_amdgcn_permlane32_swap((int)Q[5], (int)Q[7], false, false);
        f16x8 Br = mk_frag((unsigned)v02[0], (unsigned)v13[0], (unsigned)v02[1], (unsigned)v13[1]);
        a2 = __builtin_amdgcn_mfma_f32_32x32x16_f16(A21, Br, a2, 0, 0, 0);
    }

    // L3: o = b3 + sum w3[row]*tanh(pre2[row]); all f32
    float pA = 0.0f, pB = 0.0f;
#pragma unroll
    for (int m = 0; m < 16; ++m) {
        pA = fmaf(w3v[m], tanh_rat(a1[m]), pA);
        pB = fmaf(w3v[m], tanh_rat(a2[m]), pB);
    }
    auto c = __builtin_amdgcn_permlane32_swap(__float_as_int(pA), __float_as_int(pB), false, false);
    float o = b3v + __int_as_float(c[0]) + __int_as_float(c[1]);
    return __logf(1.0f + __expf(o));   // softplus; |o| <~ 6
}

__global__ __launch_bounds__(256, 1) void gamma_rk4_mfma(
        const float4* __restrict__ inp, const float* __restrict__ gamma,
        const float* __restrict__ W1, const float* __restrict__ b1,
        const float* __restrict__ W2, const float* __restrict__ b2,
        const float* __restrict__ W3, const float* __restrict__ b3,
        float* __restrict__ out, int B)
{
    int idx  = blockIdx.x * 256 + threadIdx.x;
    int lane = threadIdx.x & 63;
    int hi   = lane >> 5;
    int arow = lane & 31;

    // L1 A-frag: lane holds A[row=l&31][k=8*(l>>5)+i]; k0=W1[0][j], k1=W1[1][j]
    f16x8 A1;
    {
        unsigned p10 = cvtpk_u(W1[arow], W1[32 + arow]);
        A1 = hi ? mk_frag(0u, 0u, 0u, 0u) : mk_frag(p10, 0u, 0u, 0u);
    }
    // L2 A = W2^T in f16 (two K=16 chunks): A[j][k] = W2[k][j]
    f16x8 A2[2];
#pragma unroll
    for (int s = 0; s < 2; ++s) {
        unsigned w[4];
#pragma unroll
        for (int m = 0; m < 4; ++m) {
            w[m] = cvtpk_u(W2[(16*s + 8*hi + 2*m    ) * 32 + arow],
                           W2[(16*s + 8*hi + 2*m + 1) * 32 + arow]);
        }
        A2[s] = mk_frag(w[0], w[1], w[2], w[3]);
    }
    // C/D row map: row = (r&3) + 8*(r>>2) + 4*hi
    f32x16 b1v, b2v, w3v;
#pragma unroll
    for (int r = 0; r < 16; ++r) {
        int row = (r & 3) + 8 * (r >> 2) + 4 * hi;
        b1v[r] = b1[row];
        b2v[r] = b2[row];
        w3v[r] = W3[row];
    }
    float b3v = b3[0];

    if (idx >= B) return;
    float4 v  = inp[idx];                 // eps_n, eps_half, eps_one, dt
    float g0  = gamma[idx];

    float k1 = v.w * mlp_f(v.x, g0, A1, b1v, A2[0], A2[1], b2v, w3v, b3v) * (v.x - g0);
    float g1 = fmaf(0.5f, k1, g0);
    float k2 = v.w * mlp_f(v.y, g1, A1, b1v, A2[0], A2[1], b2v, w3v, b3v) * (v.y - g1);
    float g2 = fmaf(0.5f, k2, g0);
    float k3 = v.w * mlp_f(v.y, g2, A1, b1v, A2[0], A2[1], b2v, w3v, b3v) * (v.y - g2);
    float g3 = g0 + k3;
    float k4 = v.w * mlp_f(v.z, g3, A1, b1v, A2[0], A2[1], b2v, w3v, b3v) * (v.z - g3);

    out[idx] = g0 + (k1 + 2.0f * (k2 + k3) + k4) * (1.0f / 6.0f);
}

extern "C" void kernel_launch(void* const* d_in, const int* in_sizes, int n_in,
                              void* d_out, int out_size, void* d_ws, size_t ws_size,
                              hipStream_t stream) {
    const float4* inp   = (const float4*)d_in[0];
    const float*  gamma = (const float*)d_in[1];
    const float*  W1    = (const float*)d_in[2];
    const float*  b1    = (const float*)d_in[3];
    const float*  W2    = (const float*)d_in[4];
    const float*  b2    = (const float*)d_in[5];
    const float*  W3    = (const float*)d_in[6];
    const float*  b3    = (const float*)d_in[7];
    float* out = (float*)d_out;

    int B = in_sizes[1];
    int block = 256;
    int grid = (B + block - 1) / block;
    gamma_rk4_mfma<<<grid, block, 0, stream>>>(inp, gamma, W1, b1, W2, b2,
                                               W3, b3, out, B);
}

// Round 10
// 60.452 us; speedup vs baseline: 1.4939x; 1.4939x over previous
//
#include <hip/hip_runtime.h>

typedef _Float16 f16x8 __attribute__((ext_vector_type(8)));
typedef float f32x16 __attribute__((ext_vector_type(16)));

#define C2LE 2.8853900817779268f     // 2*log2(e)
#define NEG2C (-5.7707801635558537f) // -2*C2LE

static __device__ __forceinline__ unsigned cvtpk_u(float a, float b) {
    unsigned r;
    asm("v_cvt_pkrtz_f16_f32 %0, %1, %2" : "=v"(r) : "v"(a), "v"(b));
    return r;
}
static __device__ __forceinline__ float exp2_r(float x) {
    float r; asm("v_exp_f32 %0, %1" : "=v"(r) : "v"(x)); return r;
}
static __device__ __forceinline__ f16x8 mk_frag(unsigned a, unsigned b, unsigned c, unsigned d) {
    union { unsigned u[4]; f16x8 v; } x;
    x.u[0]=a; x.u[1]=b; x.u[2]=c; x.u[3]=d; return x.v;
}

// sigma(x) = 1/(1 + 2^x): ONE trans op (v_exp_f32) + magic+1NR reciprocal
// (3 full-rate ops, rel err ~1.2e-3 — same class R6 passed with).
// tanh(pre) = 1 - 2*sigma(c*pre) is folded into A2/w3m/o0 downstream.
static __device__ __forceinline__ float sig1(float x) {
    float d  = exp2_r(x) + 1.0f;
    float r0 = __uint_as_float(0x7EF127EAu - __float_as_uint(d));
    return r0 * fmaf(-d, r0, 2.0f);
}

static __device__ __forceinline__ float mlp_f(float e, float g,
        f16x8 A1, const f32x16& cb1v,
        f16x8 A20, f16x8 A21, const f32x16& cb2v,
        const f32x16& w3m, float o0)
{
    // L1 B-operand: k0=e, k1=g, rest 0 (raw f16; c lives in A1/cb1v)
    unsigned w0 = cvtpk_u(e, g);
    auto s0 = __builtin_amdgcn_permlane32_swap((int)w0, 0, false, false);
    f16x8 Bg1 = mk_frag((unsigned)s0[0], 0u, 0u, 0u);
    f16x8 Bg2 = mk_frag((unsigned)s0[1], 0u, 0u, 0u);
    f32x16 d1 = __builtin_amdgcn_mfma_f32_32x32x16_f16(A1, Bg1, cb1v, 0, 0, 0);
    f32x16 d2 = __builtin_amdgcn_mfma_f32_32x32x16_f16(A1, Bg2, cb1v, 0, 0, 0);

    // sigma bank 1: r = sig1(c*pre1), packed f16 pairs
    unsigned P[8], Q[8];
#pragma unroll
    for (int m = 0; m < 8; ++m) {
        P[m] = cvtpk_u(sig1(d1[2*m]), sig1(d1[2*m+1]));
        Q[m] = cvtpk_u(sig1(d2[2*m]), sig1(d2[2*m+1]));
    }

    // L2: acc = A' @ r + cb2v   (A' = -2c*W2^T; routing verified R5/R7/R8/R9)
    f32x16 a1, a2;
    {
        auto u02 = __builtin_amdgcn_permlane32_swap((int)P[0], (int)P[2], false, false);
        auto u13 = __builtin_amdgcn_permlane32_swap((int)P[1], (int)P[3], false, false);
        f16x8 Bq = mk_frag((unsigned)u02[0], (unsigned)u13[0], (unsigned)u02[1], (unsigned)u13[1]);
        a1 = __builtin_amdgcn_mfma_f32_32x32x16_f16(A20, Bq, cb2v, 0, 0, 0);
        auto v02 = __builtin_amdgcn_permlane32_swap((int)P[4], (int)P[6], false, false);
        auto v13 = __builtin_amdgcn_permlane32_swap((int)P[5], (int)P[7], false, false);
        f16x8 Br = mk_frag((unsigned)v02[0], (unsigned)v13[0], (unsigned)v02[1], (unsigned)v13[1]);
        a1 = __builtin_amdgcn_mfma_f32_32x32x16_f16(A21, Br, a1, 0, 0, 0);
    }
    {
        auto u02 = __builtin_amdgcn_permlane32_swap((int)Q[0], (int)Q[2], false, false);
        auto u13 = __builtin_amdgcn_permlane32_swap((int)Q[1], (int)Q[3], false, false);
        f16x8 Bq = mk_frag((unsigned)u02[0], (unsigned)u13[0], (unsigned)u02[1], (unsigned)u13[1]);
        a2 = __builtin_amdgcn_mfma_f32_32x32x16_f16(A20, Bq, cb2v, 0, 0, 0);
        auto v02 = __builtin_amdgcn_permlane32_swap((int)Q[4], (int)Q[6], false, false);
        auto v13 = __builtin_amdgcn_permlane32_swap((int)Q[5], (int)Q[7], false, false);
        f16x8 Br = mk_frag((unsigned)v02[0], (unsigned)v13[0], (unsigned)v02[1], (unsigned)v13[1]);
        a2 = __builtin_amdgcn_mfma_f32_32x32x16_f16(A21, Br, a2, 0, 0, 0);
    }

    // L3: o = o0 + sum w3m[r]*sig1(acc[r])   (tanh folded into w3m/o0)
    float pA = 0.0f, pB = 0.0f;
#pragma unroll
    for (int m = 0; m < 16; ++m) {
        pA = fmaf(w3m[m], sig1(a1[m]), pA);
        pB = fmaf(w3m[m], sig1(a2[m]), pB);
    }
    auto c = __builtin_amdgcn_permlane32_swap(__float_as_int(pA), __float_as_int(pB), false, false);
    float o = o0 + __int_as_float(c[0]) + __int_as_float(c[1]);
    return __logf(1.0f + __expf(o));   // softplus; |o| <~ 6
}

__global__ __launch_bounds__(256, 1) void gamma_rk4_mfma(
        const float4* __restrict__ inp, const float* __restrict__ gamma,
        const float* __restrict__ W1, const float* __restrict__ b1,
        const float* __restrict__ W2, const float* __restrict__ b2,
        const float* __restrict__ W3, const float* __restrict__ b3,
        float* __restrict__ out, int B)
{
    int idx  = blockIdx.x * 256 + threadIdx.x;
    int lane = threadIdx.x & 63;
    int hi   = lane >> 5;
    int arow = lane & 31;

    // L1 A-frag: A = c*W1 in f16; k0=c*W1[0][j], k1=c*W1[1][j]; hi lanes zero
    f16x8 A1;
    {
        unsigned p10 = cvtpk_u(C2LE * W1[arow], C2LE * W1[32 + arow]);
        A1 = hi ? mk_frag(0u, 0u, 0u, 0u) : mk_frag(p10, 0u, 0u, 0u);
    }
    // L2 A' = -2c*W2^T in f16 (two K=16 chunks): A'[j][k] = -2c*W2[k][j]
    f16x8 A2[2];
#pragma unroll
    for (int s = 0; s < 2; ++s) {
        unsigned w[4];
#pragma unroll
        for (int m = 0; m < 4; ++m) {
            w[m] = cvtpk_u(NEG2C * W2[(16*s + 8*hi + 2*m    ) * 32 + arow],
                           NEG2C * W2[(16*s + 8*hi + 2*m + 1) * 32 + arow]);
        }
        A2[s] = mk_frag(w[0], w[1], w[2], w[3]);
    }
    // C/D row map: row = (r&3) + 8*(r>>2) + 4*hi
    f32x16 cb1v, cb2v, w3m;
    float wsum = 0.0f;
#pragma unroll
    for (int r = 0; r < 16; ++r) {
        int row = (r & 3) + 8 * (r >> 2) + 4 * hi;
        cb1v[r] = C2LE * b1[row];
        cb2v[r] = C2LE * b2[row];
        float w3 = W3[row];
        w3m[r] = -2.0f * w3;
        wsum  += w3;
    }
    // cb2v += c*colsum(W2) via MFMA with B = -0.5 (exact in f16: 0xB800)
    {
        unsigned nh = 0xB800B800u;
        f16x8 negh = mk_frag(nh, nh, nh, nh);
        cb2v = __builtin_amdgcn_mfma_f32_32x32x16_f16(A2[0], negh, cb2v, 0, 0, 0);
        cb2v = __builtin_amdgcn_mfma_f32_32x32x16_f16(A2[1], negh, cb2v, 0, 0, 0);
    }
    auto sw = __builtin_amdgcn_permlane32_swap(__float_as_int(wsum), __float_as_int(wsum), false, false);
    float o0 = b3[0] + __int_as_float(sw[0]) + __int_as_float(sw[1]);

    if (idx >= B) return;
    float4 v  = inp[idx];                 // eps_n, eps_half, eps_one, dt
    float g0  = gamma[idx];

    float k1 = v.w * mlp_f(v.x, g0, A1, cb1v, A2[0], A2[1], cb2v, w3m, o0) * (v.x - g0);
    float g1 = fmaf(0.5f, k1, g0);
    float k2 = v.w * mlp_f(v.y, g1, A1, cb1v, A2[0], A2[1], cb2v, w3m, o0) * (v.y - g1);
    float g2 = fmaf(0.5f, k2, g0);
    float k3 = v.w * mlp_f(v.y, g2, A1, cb1v, A2[0], A2[1], cb2v, w3m, o0) * (v.y - g2);
    float g3 = g0 + k3;
    float k4 = v.w * mlp_f(v.z, g3, A1, cb1v, A2[0], A2[1], cb2v, w3m, o0) * (v.z - g3);

    out[idx] = g0 + (k1 + 2.0f * (k2 + k3) + k4) * (1.0f / 6.0f);
}

extern "C" void kernel_launch(void* const* d_in, const int* in_sizes, int n_in,
                              void* d_out, int out_size, void* d_ws, size_t ws_size,
                              hipStream_t stream) {
    const float4* inp   = (const float4*)d_in[0];
    const float*  gamma = (const float*)d_in[1];
    const float*  W1    = (const float*)d_in[2];
    const float*  b1    = (const float*)d_in[3];
    const float*  W2    = (const float*)d_in[4];
    const float*  b2    = (const float*)d_in[5];
    const float*  W3    = (const float*)d_in[6];
    const float*  b3    = (const float*)d_in[7];
    float* out = (float*)d_out;

    int B = in_sizes[1];
    int block = 256;
    int grid = (B + block - 1) / block;
    gamma_rk4_mfma<<<grid, block, 0, stream>>>(inp, gamma, W1, b1, W2, b2,
                                               W3, b3, out, B);
}

// Round 11
// 59.375 us; speedup vs baseline: 1.5210x; 1.0181x over previous
//
#include <hip/hip_runtime.h>

typedef _Float16 f16x8 __attribute__((ext_vector_type(8)));
typedef float f32x16 __attribute__((ext_vector_type(16)));
typedef float f32x2v __attribute__((ext_vector_type(2)));
typedef unsigned u32x2v __attribute__((ext_vector_type(2)));

#define C2LE 2.8853900817779268f     // 2*log2(e)
#define NEG2C (-5.7707801635558537f) // -2*C2LE

static __device__ __forceinline__ unsigned cvtpk_u(float a, float b) {
    unsigned r;
    asm("v_cvt_pkrtz_f16_f32 %0, %1, %2" : "=v"(r) : "v"(a), "v"(b));
    return r;
}
static __device__ __forceinline__ float exp2_r(float x) {
    float r; asm("v_exp_f32 %0, %1" : "=v"(r) : "v"(x)); return r;
}
static __device__ __forceinline__ f16x8 mk_frag(unsigned a, unsigned b, unsigned c, unsigned d) {
    union { unsigned u[4]; f16x8 v; } x;
    x.u[0]=a; x.u[1]=b; x.u[2]=c; x.u[3]=d; return x.v;
}

// Paired sigma: r_i = 1/(1 + 2^x_i) for two values. exp2 scalar (trans);
// the +1 / Newton-fma / mul expressed as f32x2 vector C ops so LLVM can
// emit packed-fp32 (v_pk_*_f32) where profitable; magic subs stay scalar.
// Same arithmetic as R10's sig1 (rel err ~1.2e-3, accepted since R6).
static __device__ __forceinline__ f32x2v sigp(float a, float b) {
    f32x2v E; E[0] = exp2_r(a); E[1] = exp2_r(b);
    f32x2v d = E + 1.0f;
    u32x2v di = __builtin_bit_cast(u32x2v, d);
    u32x2v r0i = 0x7EF127EAu - di;
    f32x2v r0 = __builtin_bit_cast(f32x2v, r0i);
    f32x2v s = -d * r0 + 2.0f;   // contracts to (pk_)fma
    return r0 * s;
}

static __device__ __forceinline__ float mlp_f(float e, float g,
        f16x8 A1, const f32x16& cb1v,
        f16x8 A20, f16x8 A21, const f32x16& cb2v,
        const f32x16& w3m, float o0)
{
    // L1 B-operand: k0=e, k1=g, rest 0 (raw f16; c lives in A1/cb1v)
    unsigned w0 = cvtpk_u(e, g);
    auto s0 = __builtin_amdgcn_permlane32_swap((int)w0, 0, false, false);
    f16x8 Bg1 = mk_frag((unsigned)s0[0], 0u, 0u, 0u);
    f16x8 Bg2 = mk_frag((unsigned)s0[1], 0u, 0u, 0u);
    f32x16 d1 = __builtin_amdgcn_mfma_f32_32x32x16_f16(A1, Bg1, cb1v, 0, 0, 0);
    f32x16 d2 = __builtin_amdgcn_mfma_f32_32x32x16_f16(A1, Bg2, cb1v, 0, 0, 0);

    // sigma bank 1: r = sig(c*pre1), packed f16 pairs
    unsigned P[8], Q[8];
#pragma unroll
    for (int m = 0; m < 8; ++m) {
        f32x2v rp = sigp(d1[2*m], d1[2*m+1]);
        P[m] = cvtpk_u(rp[0], rp[1]);
        f32x2v rq = sigp(d2[2*m], d2[2*m+1]);
        Q[m] = cvtpk_u(rq[0], rq[1]);
    }

    // L2: acc = A' @ r + cb2v   (A' = -2c*W2^T; routing verified R5/R7-R10)
    f32x16 a1, a2;
    {
        auto u02 = __builtin_amdgcn_permlane32_swap((int)P[0], (int)P[2], false, false);
        auto u13 = __builtin_amdgcn_permlane32_swap((int)P[1], (int)P[3], false, false);
        f16x8 Bq = mk_frag((unsigned)u02[0], (unsigned)u13[0], (unsigned)u02[1], (unsigned)u13[1]);
        a1 = __builtin_amdgcn_mfma_f32_32x32x16_f16(A20, Bq, cb2v, 0, 0, 0);
        auto v02 = __builtin_amdgcn_permlane32_swap((int)P[4], (int)P[6], false, false);
        auto v13 = __builtin_amdgcn_permlane32_swap((int)P[5], (int)P[7], false, false);
        f16x8 Br = mk_frag((unsigned)v02[0], (unsigned)v13[0], (unsigned)v02[1], (unsigned)v13[1]);
        a1 = __builtin_amdgcn_mfma_f32_32x32x16_f16(A21, Br, a1, 0, 0, 0);
    }
    {
        auto u02 = __builtin_amdgcn_permlane32_swap((int)Q[0], (int)Q[2], false, false);
        auto u13 = __builtin_amdgcn_permlane32_swap((int)Q[1], (int)Q[3], false, false);
        f16x8 Bq = mk_frag((unsigned)u02[0], (unsigned)u13[0], (unsigned)u02[1], (unsigned)u13[1]);
        a2 = __builtin_amdgcn_mfma_f32_32x32x16_f16(A20, Bq, cb2v, 0, 0, 0);
        auto v02 = __builtin_amdgcn_permlane32_swap((int)Q[4], (int)Q[6], false, false);
        auto v13 = __builtin_amdgcn_permlane32_swap((int)Q[5], (int)Q[7], false, false);
        f16x8 Br = mk_frag((unsigned)v02[0], (unsigned)v13[0], (unsigned)v02[1], (unsigned)v13[1]);
        a2 = __builtin_amdgcn_mfma_f32_32x32x16_f16(A21, Br, a2, 0, 0, 0);
    }

    // L3: o = o0 + sum w3m[r]*sig(acc[r]) — paired accumulate
    f32x2v accA = {0.0f, 0.0f}, accB = {0.0f, 0.0f};
#pragma unroll
    for (int m = 0; m < 8; ++m) {
        f32x2v wp; wp[0] = w3m[2*m]; wp[1] = w3m[2*m+1];
        f32x2v tA = sigp(a1[2*m], a1[2*m+1]);
        accA = wp * tA + accA;
        f32x2v tB = sigp(a2[2*m], a2[2*m+1]);
        accB = wp * tB + accB;
    }
    float pA = accA[0] + accA[1];
    float pB = accB[0] + accB[1];
    auto c = __builtin_amdgcn_permlane32_swap(__float_as_int(pA), __float_as_int(pB), false, false);
    float o = o0 + __int_as_float(c[0]) + __int_as_float(c[1]);
    return __logf(1.0f + __expf(o));   // softplus; |o| <~ 6
}

__global__ __launch_bounds__(256, 1) void gamma_rk4_mfma(
        const float4* __restrict__ inp, const float* __restrict__ gamma,
        const float* __restrict__ W1, const float* __restrict__ b1,
        const float* __restrict__ W2, const float* __restrict__ b2,
        const float* __restrict__ W3, const float* __restrict__ b3,
        float* __restrict__ out, int B)
{
    int idx  = blockIdx.x * 256 + threadIdx.x;
    int lane = threadIdx.x & 63;
    int hi   = lane >> 5;
    int arow = lane & 31;

    // L1 A-frag: A = c*W1 in f16; k0=c*W1[0][j], k1=c*W1[1][j]; hi lanes zero
    f16x8 A1;
    {
        unsigned p10 = cvtpk_u(C2LE * W1[arow], C2LE * W1[32 + arow]);
        A1 = hi ? mk_frag(0u, 0u, 0u, 0u) : mk_frag(p10, 0u, 0u, 0u);
    }
    // L2 A' = -2c*W2^T in f16 (two K=16 chunks): A'[j][k] = -2c*W2[k][j]
    f16x8 A2[2];
#pragma unroll
    for (int s = 0; s < 2; ++s) {
        unsigned w[4];
#pragma unroll
        for (int m = 0; m < 4; ++m) {
            w[m] = cvtpk_u(NEG2C * W2[(16*s + 8*hi + 2*m    ) * 32 + arow],
                           NEG2C * W2[(16*s + 8*hi + 2*m + 1) * 32 + arow]);
        }
        A2[s] = mk_frag(w[0], w[1], w[2], w[3]);
    }
    // C/D row map: row = (r&3) + 8*(r>>2) + 4*hi
    f32x16 cb1v, cb2v, w3m;
    float wsum = 0.0f;
#pragma unroll
    for (int r = 0; r < 16; ++r) {
        int row = (r & 3) + 8 * (r >> 2) + 4 * hi;
        cb1v[r] = C2LE * b1[row];
        cb2v[r] = C2LE * b2[row];
        float w3 = W3[row];
        w3m[r] = -2.0f * w3;
        wsum  += w3;
    }
    // cb2v += c*colsum(W2) via MFMA with B = -0.5 (exact in f16: 0xB800)
    {
        unsigned nh = 0xB800B800u;
        f16x8 negh = mk_frag(nh, nh, nh, nh);
        cb2v = __builtin_amdgcn_mfma_f32_32x32x16_f16(A2[0], negh, cb2v, 0, 0, 0);
        cb2v = __builtin_amdgcn_mfma_f32_32x32x16_f16(A2[1], negh, cb2v, 0, 0, 0);
    }
    auto sw = __builtin_amdgcn_permlane32_swap(__float_as_int(wsum), __float_as_int(wsum), false, false);
    float o0 = b3[0] + __int_as_float(sw[0]) + __int_as_float(sw[1]);

    if (idx >= B) return;
    float4 v  = inp[idx];                 // eps_n, eps_half, eps_one, dt
    float g0  = gamma[idx];

    float k1 = v.w * mlp_f(v.x, g0, A1, cb1v, A2[0], A2[1], cb2v, w3m, o0) * (v.x - g0);
    float g1 = fmaf(0.5f, k1, g0);
    float k2 = v.w * mlp_f(v.y, g1, A1, cb1v, A2[0], A2[1], cb2v, w3m, o0) * (v.y - g1);
    float g2 = fmaf(0.5f, k2, g0);
    float k3 = v.w * mlp_f(v.y, g2, A1, cb1v, A2[0], A2[1], cb2v, w3m, o0) * (v.y - g2);
    float g3 = g0 + k3;
    float k4 = v.w * mlp_f(v.z, g3, A1, cb1v, A2[0], A2[1], cb2v, w3m, o0) * (v.z - g3);

    out[idx] = g0 + (k1 + 2.0f * (k2 + k3) + k4) * (1.0f / 6.0f);
}

extern "C" void kernel_launch(void* const* d_in, const int* in_sizes, int n_in,
                              void* d_out, int out_size, void* d_ws, size_t ws_size,
                              hipStream_t stream) {
    const float4* inp   = (const float4*)d_in[0];
    const float*  gamma = (const float*)d_in[1];
    const float*  W1    = (const float*)d_in[2];
    const float*  b1    = (const float*)d_in[3];
    const float*  W2    = (const float*)d_in[4];
    const float*  b2    = (const float*)d_in[5];
    const float*  W3    = (const float*)d_in[6];
    const float*  b3    = (const float*)d_in[7];
    float* out = (float*)d_out;

    int B = in_sizes[1];
    int block = 256;
    int grid = (B + block - 1) / block;
    gamma_rk4_mfma<<<grid, block, 0, stream>>>(inp, gamma, W1, b1, W2, b2,
                                               W3, b3, out, B);
}

// Round 12
// 57.967 us; speedup vs baseline: 1.5580x; 1.0243x over previous
//
#include <hip/hip_runtime.h>

typedef _Float16 f16x8 __attribute__((ext_vector_type(8)));
typedef float f32x16 __attribute__((ext_vector_type(16)));
typedef float f32x2v __attribute__((ext_vector_type(2)));
typedef unsigned u32x2v __attribute__((ext_vector_type(2)));

#define C2LE 2.8853900817779268f     // 2*log2(e)
#define NEG2C (-5.7707801635558537f) // -2*C2LE

static __device__ __forceinline__ unsigned cvtpk_u(float a, float b) {
    unsigned r;
    asm("v_cvt_pkrtz_f16_f32 %0, %1, %2" : "=v"(r) : "v"(a), "v"(b));
    return r;
}
static __device__ __forceinline__ float exp2_r(float x) {
    float r; asm("v_exp_f32 %0, %1" : "=v"(r) : "v"(x)); return r;
}
static __device__ __forceinline__ f16x8 mk_frag(unsigned a, unsigned b, unsigned c, unsigned d) {
    union { unsigned u[4]; f16x8 v; } x;
    x.u[0]=a; x.u[1]=b; x.u[2]=c; x.u[3]=d; return x.v;
}

// Paired sigma: r_i = 1/(1+2^x_i); scalar exp2 (trans) + pk-f32 magic-NR rcp.
static __device__ __forceinline__ f32x2v sigp(float a, float b) {
    f32x2v E; E[0] = exp2_r(a); E[1] = exp2_r(b);
    f32x2v d = E + 1.0f;
    u32x2v di = __builtin_bit_cast(u32x2v, d);
    u32x2v r0i = 0x7EF127EAu - di;
    f32x2v r0 = __builtin_bit_cast(f32x2v, r0i);
    f32x2v s = -d * r0 + 2.0f;
    return r0 * s;
}

// One L2 bank: acc = A' @ r + cb2v from 8 packed sigma pairs.
static __device__ __forceinline__ f32x16 l2_bank(const unsigned* P,
        f16x8 A20, f16x8 A21, const f32x16& cb2v)
{
    auto u02 = __builtin_amdgcn_permlane32_swap((int)P[0], (int)P[2], false, false);
    auto u13 = __builtin_amdgcn_permlane32_swap((int)P[1], (int)P[3], false, false);
    f16x8 Bq = mk_frag((unsigned)u02[0], (unsigned)u13[0], (unsigned)u02[1], (unsigned)u13[1]);
    f32x16 a = __builtin_amdgcn_mfma_f32_32x32x16_f16(A20, Bq, cb2v, 0, 0, 0);
    auto v02 = __builtin_amdgcn_permlane32_swap((int)P[4], (int)P[6], false, false);
    auto v13 = __builtin_amdgcn_permlane32_swap((int)P[5], (int)P[7], false, false);
    f16x8 Br = mk_frag((unsigned)v02[0], (unsigned)v13[0], (unsigned)v02[1], (unsigned)v13[1]);
    return __builtin_amdgcn_mfma_f32_32x32x16_f16(A21, Br, a, 0, 0, 0);
}

// Two-element MLP: e/g hold elem0 in lane .0, elem1 in lane .1.
static __device__ __forceinline__ f32x2v mlp_f2(f32x2v e, f32x2v g,
        f16x8 A1, const f32x16& cb1v,
        f16x8 A20, f16x8 A21, const f32x16& cb2v,
        const f32x16& w3m, float o0)
{
    unsigned wA = cvtpk_u(e[0], g[0]);
    unsigned wB = cvtpk_u(e[1], g[1]);
    auto sA = __builtin_amdgcn_permlane32_swap((int)wA, 0, false, false);
    auto sB = __builtin_amdgcn_permlane32_swap((int)wB, 0, false, false);
    f32x16 d1a = __builtin_amdgcn_mfma_f32_32x32x16_f16(A1, mk_frag((unsigned)sA[0],0u,0u,0u), cb1v, 0, 0, 0);
    f32x16 d2a = __builtin_amdgcn_mfma_f32_32x32x16_f16(A1, mk_frag((unsigned)sA[1],0u,0u,0u), cb1v, 0, 0, 0);
    f32x16 d1b = __builtin_amdgcn_mfma_f32_32x32x16_f16(A1, mk_frag((unsigned)sB[0],0u,0u,0u), cb1v, 0, 0, 0);
    f32x16 d2b = __builtin_amdgcn_mfma_f32_32x32x16_f16(A1, mk_frag((unsigned)sB[1],0u,0u,0u), cb1v, 0, 0, 0);

    unsigned Pa[8], Qa[8], Pb[8], Qb[8];
#pragma unroll
    for (int m = 0; m < 8; ++m) {
        f32x2v r0 = sigp(d1a[2*m], d1a[2*m+1]);  Pa[m] = cvtpk_u(r0[0], r0[1]);
        f32x2v r1 = sigp(d2a[2*m], d2a[2*m+1]);  Qa[m] = cvtpk_u(r1[0], r1[1]);
        f32x2v r2 = sigp(d1b[2*m], d1b[2*m+1]);  Pb[m] = cvtpk_u(r2[0], r2[1]);
        f32x2v r3 = sigp(d2b[2*m], d2b[2*m+1]);  Qb[m] = cvtpk_u(r3[0], r3[1]);
    }

    f32x16 a1a = l2_bank(Pa, A20, A21, cb2v);
    f32x16 a2a = l2_bank(Qa, A20, A21, cb2v);
    f32x16 a1b = l2_bank(Pb, A20, A21, cb2v);
    f32x16 a2b = l2_bank(Qb, A20, A21, cb2v);

    f32x2v accAa = {0.0f,0.0f}, accBa = {0.0f,0.0f};
    f32x2v accAb = {0.0f,0.0f}, accBb = {0.0f,0.0f};
#pragma unroll
    for (int m = 0; m < 8; ++m) {
        f32x2v wp; wp[0] = w3m[2*m]; wp[1] = w3m[2*m+1];
        accAa = wp * sigp(a1a[2*m], a1a[2*m+1]) + accAa;
        accBa = wp * sigp(a2a[2*m], a2a[2*m+1]) + accBa;
        accAb = wp * sigp(a1b[2*m], a1b[2*m+1]) + accAb;
        accBb = wp * sigp(a2b[2*m], a2b[2*m+1]) + accBb;
    }
    float pAa = accAa[0] + accAa[1], pBa = accBa[0] + accBa[1];
    float pAb = accAb[0] + accAb[1], pBb = accBb[0] + accBb[1];
    auto ca = __builtin_amdgcn_permlane32_swap(__float_as_int(pAa), __float_as_int(pBa), false, false);
    auto cb = __builtin_amdgcn_permlane32_swap(__float_as_int(pAb), __float_as_int(pBb), false, false);
    float oa = o0 + __int_as_float(ca[0]) + __int_as_float(ca[1]);
    float ob = o0 + __int_as_float(cb[0]) + __int_as_float(cb[1]);
    f32x2v out;
    out[0] = __logf(1.0f + __expf(oa));
    out[1] = __logf(1.0f + __expf(ob));
    return out;
}

__global__ __launch_bounds__(256) void gamma_rk4_mfma(
        const float4* __restrict__ inp, const float* __restrict__ gamma,
        const float* __restrict__ W1, const float* __restrict__ b1,
        const float* __restrict__ W2, const float* __restrict__ b2,
        const float* __restrict__ W3, const float* __restrict__ b3,
        float* __restrict__ out, int B)
{
    int idx  = blockIdx.x * 256 + threadIdx.x;
    int lane = threadIdx.x & 63;
    int hi   = lane >> 5;
    int arow = lane & 31;

    // L1 A-frag: A = c*W1 in f16; k0=c*W1[0][j], k1=c*W1[1][j]; hi lanes zero
    f16x8 A1;
    {
        unsigned p10 = cvtpk_u(C2LE * W1[arow], C2LE * W1[32 + arow]);
        A1 = hi ? mk_frag(0u, 0u, 0u, 0u) : mk_frag(p10, 0u, 0u, 0u);
    }
    // L2 A' = -2c*W2^T in f16 (two K=16 chunks)
    f16x8 A2[2];
#pragma unroll
    for (int s = 0; s < 2; ++s) {
        unsigned w[4];
#pragma unroll
        for (int m = 0; m < 4; ++m) {
            w[m] = cvtpk_u(NEG2C * W2[(16*s + 8*hi + 2*m    ) * 32 + arow],
                           NEG2C * W2[(16*s + 8*hi + 2*m + 1) * 32 + arow]);
        }
        A2[s] = mk_frag(w[0], w[1], w[2], w[3]);
    }
    // C/D row map: row = (r&3) + 8*(r>>2) + 4*hi
    f32x16 cb1v, cb2v, w3m;
    float wsum = 0.0f;
#pragma unroll
    for (int r = 0; r < 16; ++r) {
        int row = (r & 3) + 8 * (r >> 2) + 4 * hi;
        cb1v[r] = C2LE * b1[row];
        cb2v[r] = C2LE * b2[row];
        float w3 = W3[row];
        w3m[r] = -2.0f * w3;
        wsum  += w3;
    }
    // cb2v += c*colsum(W2) via MFMA with B = -0.5 (exact in f16: 0xB800)
    {
        unsigned nh = 0xB800B800u;
        f16x8 negh = mk_frag(nh, nh, nh, nh);
        cb2v = __builtin_amdgcn_mfma_f32_32x32x16_f16(A2[0], negh, cb2v, 0, 0, 0);
        cb2v = __builtin_amdgcn_mfma_f32_32x32x16_f16(A2[1], negh, cb2v, 0, 0, 0);
    }
    auto sw = __builtin_amdgcn_permlane32_swap(__float_as_int(wsum), __float_as_int(wsum), false, false);
    float o0 = b3[0] + __int_as_float(sw[0]) + __int_as_float(sw[1]);

    int i0 = 2 * idx;
    if (i0 >= B) return;
    float4 va = inp[i0];
    float4 vb = inp[i0 + 1];
    float2 gg = *reinterpret_cast<const float2*>(gamma + i0);

    f32x2v g0v = {gg.x, gg.y};
    f32x2v e_n = {va.x, vb.x}, e_h = {va.y, vb.y}, e_o = {va.z, vb.z};
    f32x2v dt  = {va.w, vb.w};

    f32x2v k1 = dt * mlp_f2(e_n, g0v, A1, cb1v, A2[0], A2[1], cb2v, w3m, o0) * (e_n - g0v);
    f32x2v g1 = 0.5f * k1 + g0v;
    f32x2v k2 = dt * mlp_f2(e_h, g1,  A1, cb1v, A2[0], A2[1], cb2v, w3m, o0) * (e_h - g1);
    f32x2v g2 = 0.5f * k2 + g0v;
    f32x2v k3 = dt * mlp_f2(e_h, g2,  A1, cb1v, A2[0], A2[1], cb2v, w3m, o0) * (e_h - g2);
    f32x2v g3 = g0v + k3;
    f32x2v k4 = dt * mlp_f2(e_o, g3,  A1, cb1v, A2[0], A2[1], cb2v, w3m, o0) * (e_o - g3);

    f32x2v res = g0v + (k1 + 2.0f * (k2 + k3) + k4) * (1.0f / 6.0f);
    float2 ro; ro.x = res[0]; ro.y = res[1];
    *reinterpret_cast<float2*>(out + i0) = ro;
}

extern "C" void kernel_launch(void* const* d_in, const int* in_sizes, int n_in,
                              void* d_out, int out_size, void* d_ws, size_t ws_size,
                              hipStream_t stream) {
    const float4* inp   = (const float4*)d_in[0];
    const float*  gamma = (const float*)d_in[1];
    const float*  W1    = (const float*)d_in[2];
    const float*  b1    = (const float*)d_in[3];
    const float*  W2    = (const float*)d_in[4];
    const float*  b2    = (const float*)d_in[5];
    const float*  W3    = (const float*)d_in[6];
    const float*  b3    = (const float*)d_in[7];
    float* out = (float*)d_out;

    int B = in_sizes[1];
    int threads = (B + 1) / 2;
    int block = 256;
    int grid = (threads + block - 1) / block;
    gamma_rk4_mfma<<<grid, block, 0, stream>>>(inp, gamma, W1, b1, W2, b2,
                                               W3, b3, out, B);
}